// Round 11
// baseline (235.200 us; speedup 1.0000x reference)
//
#include <hip/hip_runtime.h>
#include <hip/hip_bf16.h>

// DisenHAN fused, MFMA split-bf16 edition, v7 (gfx950).
// v7: occupancy bump. v6's register-resident routing cut VGPR to 68 and LDS
// to 26.6KB, but launch_bounds(256,3) still capped residency at 3 blocks/CU
// (measured ~2, Occupancy 25%) while VALUBusy=47%/MfmaUtil=13% show both
// pipes half-idle (latency-bound on L3/HBM gathers + shuffle chains).
// -> __launch_bounds__(256,5): VGPR cap 102 (>68 used, no spill risk),
//    5 blocks/CU, 20 waves/CU; LDS 5x26.6=133KB < 160KB.
// v6 recap: routing lane map (rr=lane>>4 rows, j4=lane&15 cols): one b128
// pass per iteration feeds logits AND z; softmax + z reduced via shfl_xor;
// htmp register-resident; bank conflicts 4.8M->1.18M.
// Base: separate 4-block pack kernel (pk fragments in d_ws), cvt_pk split,
// early gathers, per-slot prefetch.
// 3-pass split-bf16 MFMA: A_hi*W_hi + A_lo*W_hi + A_hi*W_lo (~fp32 accuracy).
// T=1 collapses hete-attention: beta==1, wp==1 forever.

#define NTH 256

typedef __attribute__((ext_vector_type(8))) short bf16x8;   // 8 bf16 (4 VGPRs)
typedef __attribute__((ext_vector_type(4))) float floatx4;

__device__ __forceinline__ short f2bf(float f) {            // RNE fp32->bf16 (pack kernel)
    unsigned u = __builtin_bit_cast(unsigned, f);
    unsigned r = u + 0x7fffu + ((u >> 16) & 1u);
    return (short)(r >> 16);
}
__device__ __forceinline__ float bf2f_s(short h) {
    return __builtin_bit_cast(float, (unsigned)((unsigned short)h) << 16);
}

// pack two fp32 -> one dword of two bf16 (v_cvt_pk_bf16_f32)
__device__ __forceinline__ unsigned cvt_pk_bf16(float x0, float x1) {
    __hip_bfloat162 h2 = __float22bfloat162_rn(make_float2(x0, x1));
    unsigned u;
    __builtin_memcpy(&u, &h2, 4);
    return u;
}

// split x -> hi + lo bf16 via packed cvt
__device__ __forceinline__ void split_pack8(float4 a, float4 b, bf16x8& hi, bf16x8& lo) {
    float v[8] = {a.x, a.y, a.z, a.w, b.x, b.y, b.z, b.w};
    unsigned hp[4], lp[4];
#pragma unroll
    for (int i = 0; i < 4; ++i) {
        float x0 = v[2 * i], x1 = v[2 * i + 1];
        unsigned hb = cvt_pk_bf16(x0, x1);
        hp[i] = hb;
        float r0 = x0 - __builtin_bit_cast(float, hb << 16);
        float r1 = x1 - __builtin_bit_cast(float, hb & 0xffff0000u);
        lp[i] = cvt_pk_bf16(r0, r1);
    }
    hi = __builtin_bit_cast(bf16x8, (uint4){hp[0], hp[1], hp[2], hp[3]});
    lo = __builtin_bit_cast(bf16x8, (uint4){lp[0], lp[1], lp[2], lp[3]});
}

__device__ __forceinline__ floatx4 mfma3(bf16x8 Ah, bf16x8 Al, bf16x8 Wh, bf16x8 Wl,
                                         floatx4 acc) {
    acc = __builtin_amdgcn_mfma_f32_16x16x32_bf16(Ah, Wh, acc, 0, 0, 0);
    acc = __builtin_amdgcn_mfma_f32_16x16x32_bf16(Al, Wh, acc, 0, 0, 0);
    acc = __builtin_amdgcn_mfma_f32_16x16x32_bf16(Ah, Wl, acc, 0, 0, 0);
    return acc;
}

// ---- setup: pack 4 weight matrices into B-fragment order, hi/lo split ----
__global__ void pack_weights(const float* __restrict__ W0u, const float* __restrict__ W0i,
                             const float* __restrict__ W1u, const float* __restrict__ W1i,
                             short* __restrict__ pk) {
    const float* Ws[4] = {W0u, W0i, W1u, W1i};
    const int w = blockIdx.x;
    const int wv = threadIdx.x >> 6, lane = threadIdx.x & 63;
    const int quad = lane >> 4, m16 = lane & 15;
    const int nt = wv;
    const float* W = Ws[w];
#pragma unroll
    for (int ks = 0; ks < 2; ++ks) {
        bf16x8 fh, fl;
#pragma unroll
        for (int j = 0; j < 8; ++j) {
            float x = W[(ks * 32 + quad * 8 + j) * 64 + nt * 16 + m16];
            short h = f2bf(x);
            fh[j] = h;
            fl[j] = f2bf(x - bf2f_s(h));
        }
        long base = (long)(((w * 4 + nt) * 2 + ks) * 2) * 64 + lane;
        ((bf16x8*)pk)[base] = fh;
        ((bf16x8*)pk)[base + 64] = fl;
    }
}

__global__ __launch_bounds__(256, 5)
void disenhan_mfma(const float* __restrict__ user_table,
                   const float* __restrict__ item_table,
                   const bf16x8* __restrict__ pk,
                   const int* __restrict__ uidx0, const int* __restrict__ uidx1,
                   const int* __restrict__ uidx2,
                   const int* __restrict__ iidx0, const int* __restrict__ iidx1,
                   const int* __restrict__ iidx2,
                   float* __restrict__ out, int B)
{
    constexpr float SCALE = 0.35355339059327373f;  // 1/sqrt(8)
    const int b = blockIdx.x, branch = blockIdx.y;
    const int tid = threadIdx.x;
    const int wv = tid >> 6, lane = tid & 63;
    const int quad = lane >> 4;   // MFMA k-block selector
    const int m16  = lane & 15;   // MFMA row (A) / col (B,D) selector
    const int rr   = lane >> 4;   // routing: row group (rows 4rr..4rr+3)
    const int j4   = lane & 15;   // routing: col group (cols 4j4..4j4+3)

    // matrix ids in pk: 0=W0u 1=W0i 2=W1u 3=W1i
    const float *tab0, *tab1;
    const int *idx0, *idx1, *idx2;
    int w1c_id, w1n_id, w0n_id;
    if (branch == 0) { tab0 = user_table; tab1 = item_table;
                       idx0 = uidx0; idx1 = uidx1; idx2 = uidx2;
                       w1c_id = 3; w1n_id = 2; w0n_id = 1; }
    else             { tab0 = item_table; tab1 = user_table;
                       idx0 = iidx0; idx1 = iidx1; idx2 = iidx2;
                       w1c_id = 2; w1n_id = 3; w0n_id = 0; }

    __shared__ float sN[4][16 * 68];  // per-wave nh tile (fp32, pitch 68)
    __shared__ float sC[16 * 68];     // hid (= c), pitch 68
    __shared__ float sH[16 * 68];     // h1 (written once per slot at the end)
    __shared__ float sE0[64];         // layer-0 center (e0)

    // e0 prefetch (consumed by wave 0 at the end; loaded by all, uniform)
    const float v0 = tab0[(long)idx0[b] * 64 + lane];

    // ---- B-fragment loader: 16 coalesced 16B loads from the packed buffer ----
    bf16x8 wfh[4][2], wfl[4][2];
    auto load_wfrag = [&](int w) {
#pragma unroll
        for (int nt = 0; nt < 4; ++nt)
#pragma unroll
            for (int ks = 0; ks < 2; ++ks) {
                long base = (long)(((w * 4 + nt) * 2 + ks) * 2) * 64 + lane;
                wfh[nt][ks] = pk[base];
                wfl[nt][ks] = pk[base + 64];
            }
    };

    // ---- register-resident routing: 3 iterations on one s-slot ----
    auto routing_reg = [&](const float* __restrict__ Nw, float4 c4, bool relu_last)
        -> float4 {
        float4 h4 = c4;   // iter-0 htmp = hid
#pragma unroll
        for (int it = 0; it < 3; ++it) {
            float4 Nv[4];
#pragma unroll
            for (int t = 0; t < 4; ++t)
                Nv[t] = *(const float4*)&Nw[(4 * rr + t) * 68 + 4 * j4];
            // logits e[4rr+t][k2]: dot over this lane's 4 cols + pair lane's 4
            float pp[4];
#pragma unroll
            for (int t = 0; t < 4; ++t) {
                float d = h4.x * Nv[t].x + h4.y * Nv[t].y +
                          h4.z * Nv[t].z + h4.w * Nv[t].w;
                d += __shfl_xor(d, 1);        // + other half of the octet
                pp[t] = d * SCALE;
            }
            // softmax over n (16 rows): in-reg over t, shfl over rr
            float m = fmaxf(fmaxf(pp[0], pp[1]), fmaxf(pp[2], pp[3]));
            m = fmaxf(m, __shfl_xor(m, 16));
            m = fmaxf(m, __shfl_xor(m, 32));
            float e0 = __expf(pp[0] - m), e1 = __expf(pp[1] - m);
            float e2 = __expf(pp[2] - m), e3 = __expf(pp[3] - m);
            float sm = (e0 + e1) + (e2 + e3);
            sm += __shfl_xor(sm, 16);
            sm += __shfl_xor(sm, 32);
            float inv = 1.0f / sm;
            float a0 = e0 * inv, a1 = e1 * inv, a2 = e2 * inv, a3 = e3 * inv;
            // z[4j4..] partial over rows 4rr..4rr+3, then reduce over rr
            float4 z;
            z.x = a0 * Nv[0].x; z.y = a0 * Nv[0].y; z.z = a0 * Nv[0].z; z.w = a0 * Nv[0].w;
            z.x = fmaf(a1, Nv[1].x, z.x); z.y = fmaf(a1, Nv[1].y, z.y);
            z.z = fmaf(a1, Nv[1].z, z.z); z.w = fmaf(a1, Nv[1].w, z.w);
            z.x = fmaf(a2, Nv[2].x, z.x); z.y = fmaf(a2, Nv[2].y, z.y);
            z.z = fmaf(a2, Nv[2].z, z.z); z.w = fmaf(a2, Nv[2].w, z.w);
            z.x = fmaf(a3, Nv[3].x, z.x); z.y = fmaf(a3, Nv[3].y, z.y);
            z.z = fmaf(a3, Nv[3].z, z.z); z.w = fmaf(a3, Nv[3].w, z.w);
            z.x += __shfl_xor(z.x, 16); z.y += __shfl_xor(z.y, 16);
            z.z += __shfl_xor(z.z, 16); z.w += __shfl_xor(z.w, 16);
            z.x += __shfl_xor(z.x, 32); z.y += __shfl_xor(z.y, 32);
            z.z += __shfl_xor(z.z, 32); z.w += __shfl_xor(z.w, 32);
            h4.x = c4.x + z.x; h4.y = c4.y + z.y;
            h4.z = c4.z + z.z; h4.w = c4.w + z.w;
            if (relu_last && it == 2) {
                h4.x = fmaxf(h4.x, 0.f); h4.y = fmaxf(h4.y, 0.f);
                h4.z = fmaxf(h4.z, 0.f); h4.w = fmaxf(h4.w, 0.f);
            }
        }
        return h4;
    };

    // ---- 16x64 tile matmul into one sN tile (24 MFMAs) ----
    auto matmul_tile = [&](float4 f0, float4 f1, float4 f2, float4 f3,
                           float* __restrict__ Nw) {
        bf16x8 A0h, A0l, A1h, A1l;
        split_pack8(f0, f1, A0h, A0l);
        split_pack8(f2, f3, A1h, A1l);
        floatx4 acc[4];
#pragma unroll
        for (int nt = 0; nt < 4; ++nt) {
            acc[nt] = (floatx4){0.f, 0.f, 0.f, 0.f};
            acc[nt] = mfma3(A0h, A0l, wfh[nt][0], wfl[nt][0], acc[nt]);
            acc[nt] = mfma3(A1h, A1l, wfh[nt][1], wfl[nt][1], acc[nt]);
        }
#pragma unroll
        for (int nt = 0; nt < 4; ++nt)
#pragma unroll
            for (int rg = 0; rg < 4; ++rg)
                Nw[(quad * 4 + rg) * 68 + nt * 16 + m16] = acc[nt][rg];
    };

    // ---- issue long-latency gathers early ----
    const long g1 = (long)idx1[b * 16 + m16] * 64;
    const float* p1 = &tab1[g1 + quad * 8];
    float4 e1a = *(const float4*)p1;
    float4 e1b = *(const float4*)(p1 + 4);
    float4 e1c = *(const float4*)(p1 + 32);
    float4 e1d = *(const float4*)(p1 + 36);
    int gidx[4];
#pragma unroll
    for (int q = 0; q < 4; ++q)
        gidx[q] = idx2[b * 256 + (wv * 4 + q) * 16 + m16];

    // ================= layer-1 pre-encode: hid = e1 @ W1c =================
    load_wfrag(w1c_id);
    {
        bf16x8 A0h, A0l, A1h, A1l;
        split_pack8(e1a, e1b, A0h, A0l);
        split_pack8(e1c, e1d, A1h, A1l);
        floatx4 hacc[4];
#pragma unroll
        for (int nt = 0; nt < 4; ++nt) {
            hacc[nt] = (floatx4){0.f, 0.f, 0.f, 0.f};
            hacc[nt] = mfma3(A0h, A0l, wfh[nt][0], wfl[nt][0], hacc[nt]);
            hacc[nt] = mfma3(A1h, A1l, wfh[nt][1], wfl[nt][1], hacc[nt]);
        }
        // D: row = quad*4+reg, col = nt*16+m16. Wave w keeps rows w*4..w*4+3
        // (quad==wv lanes) — exactly its own routing slots. Only sC needed.
        if (quad == wv) {
#pragma unroll
            for (int nt = 0; nt < 4; ++nt)
#pragma unroll
                for (int rg = 0; rg < 4; ++rg)
                    sC[(quad * 4 + rg) * 68 + nt * 16 + m16] = hacc[nt][rg];
        }
    }
    __builtin_amdgcn_wave_barrier();

    // ================= layer-1 main: 4 s-slots per wave =================
    float4 f0, f1, f2, f3;
    {
        const float* p = &tab0[(long)gidx[0] * 64 + quad * 8];
        f0 = *(const float4*)p;        f1 = *(const float4*)(p + 4);
        f2 = *(const float4*)(p + 32); f3 = *(const float4*)(p + 36);
    }
    load_wfrag(w1n_id);
#pragma unroll
    for (int q = 0; q < 4; ++q) {
        const int s = wv * 4 + q;
        matmul_tile(f0, f1, f2, f3, sN[wv]);
        if (q < 3) {  // prefetch next slot's A rows; consumed next iteration
            const float* p = &tab0[(long)gidx[q + 1] * 64 + quad * 8];
            f0 = *(const float4*)p;        f1 = *(const float4*)(p + 4);
            f2 = *(const float4*)(p + 32); f3 = *(const float4*)(p + 36);
        }
        __builtin_amdgcn_wave_barrier();
        float4 c4 = *(const float4*)&sC[s * 68 + 4 * j4];
        float4 h4 = routing_reg(sN[wv], c4, true);
        if (rr == 0)
            *(float4*)&sH[s * 68 + 4 * j4] = h4;   // h1 row s
        __builtin_amdgcn_wave_barrier();           // sN reads done before next matmul
    }

    // ================= layer-0 =================
    __syncthreads();   // the only block barrier: all h1 rows visible
    if (wv == 0) {
        load_wfrag(w0n_id);
        sE0[lane] = v0;
        bf16x8 A0h, A0l, A1h, A1l;
        {
            const float* hp = &sH[m16 * 68];
            split_pack8(*(const float4*)&hp[quad * 8],
                        *(const float4*)&hp[quad * 8 + 4], A0h, A0l);
            split_pack8(*(const float4*)&hp[32 + quad * 8],
                        *(const float4*)&hp[32 + quad * 8 + 4], A1h, A1l);
        }
        floatx4 acc[4];
#pragma unroll
        for (int nt = 0; nt < 4; ++nt) {
            acc[nt] = (floatx4){0.f, 0.f, 0.f, 0.f};
            acc[nt] = mfma3(A0h, A0l, wfh[nt][0], wfl[nt][0], acc[nt]);
            acc[nt] = mfma3(A1h, A1l, wfh[nt][1], wfl[nt][1], acc[nt]);
        }
#pragma unroll
        for (int nt = 0; nt < 4; ++nt)
#pragma unroll
            for (int rg = 0; rg < 4; ++rg)
                sN[0][(quad * 4 + rg) * 68 + nt * 16 + m16] = acc[nt][rg];
        __builtin_amdgcn_wave_barrier();
        float4 c4 = *(const float4*)&sE0[4 * j4];
        float4 h4 = routing_reg(sN[0], c4, false);
        if (rr == 0)
            *(float4*)&out[((long)branch * B + b) * 64 + 4 * j4] = h4;
    }
}

extern "C" void kernel_launch(void* const* d_in, const int* in_sizes, int n_in,
                              void* d_out, int out_size, void* d_ws, size_t ws_size,
                              hipStream_t stream) {
    const float* user_table = (const float*)d_in[0];
    const float* item_table = (const float*)d_in[1];
    const float* W0u = (const float*)d_in[2];
    const float* W0i = (const float*)d_in[3];
    const float* W1u = (const float*)d_in[4];
    const float* W1i = (const float*)d_in[5];
    const int* uidx0 = (const int*)d_in[6];
    const int* uidx1 = (const int*)d_in[7];
    const int* uidx2 = (const int*)d_in[8];
    const int* iidx0 = (const int*)d_in[9];
    const int* iidx1 = (const int*)d_in[10];
    const int* iidx2 = (const int*)d_in[11];
    float* out = (float*)d_out;
    short* pk = (short*)d_ws;   // 4 matrices * 16 frags * 64 lanes * 16B = 64 KB

    const int B = in_sizes[6];  // 2048
    hipLaunchKernelGGL(pack_weights, dim3(4), dim3(256), 0, stream,
                       W0u, W0i, W1u, W1i, pk);
    dim3 grid(B, 2), block(NTH);
    hipLaunchKernelGGL(disenhan_mfma, grid, block, 0, stream,
                       user_table, item_table, (const bf16x8*)pk,
                       uidx0, uidx1, uidx2, iidx0, iidx1, iidx2, out, B);
}

// Round 12
// 176.136 us; speedup vs baseline: 1.3353x; 1.3353x over previous
//
#include <hip/hip_runtime.h>
#include <hip/hip_bf16.h>

// DisenHAN fused, MFMA split-bf16 edition, v8 (gfx950).
// v8: launch_bounds(256,4). Round-11's (256,5) implied a ~96-VGPR cap, below
// the kernel's real footprint (68 VGPR + 64-VGPR W-fragment file + accs) ->
// compiler forced VGPR_Count=48 with ~270MB of scratch spill (WRITE_SIZE
// 1MB->148MB), dispatch 108->151us. Rule confirmed twice (r5, r11): the
// waves/EU bound must keep 512/waves >= measured footprint. (256,4) caps at
// 128 >= need: no spill, 4 blocks/CU (was 3), 16 waves/CU.
// v6 recap: register-resident routing (rr=lane>>4 rows, j4=lane&15 cols):
// one b128 pass/iter feeds logits AND z; softmax+z via shfl_xor; htmp in
// registers; bank conflicts 1.18M. Separate 4-block pack kernel -> pk in
// d_ws; cvt_pk hi/lo split; early gathers; per-slot prefetch.
// 3-pass split-bf16 MFMA: A_hi*W_hi + A_lo*W_hi + A_hi*W_lo (~fp32 accuracy).
// T=1 collapses hete-attention: beta==1, wp==1 forever.

#define NTH 256

typedef __attribute__((ext_vector_type(8))) short bf16x8;   // 8 bf16 (4 VGPRs)
typedef __attribute__((ext_vector_type(4))) float floatx4;

__device__ __forceinline__ short f2bf(float f) {            // RNE fp32->bf16 (pack kernel)
    unsigned u = __builtin_bit_cast(unsigned, f);
    unsigned r = u + 0x7fffu + ((u >> 16) & 1u);
    return (short)(r >> 16);
}
__device__ __forceinline__ float bf2f_s(short h) {
    return __builtin_bit_cast(float, (unsigned)((unsigned short)h) << 16);
}

// pack two fp32 -> one dword of two bf16 (v_cvt_pk_bf16_f32)
__device__ __forceinline__ unsigned cvt_pk_bf16(float x0, float x1) {
    __hip_bfloat162 h2 = __float22bfloat162_rn(make_float2(x0, x1));
    unsigned u;
    __builtin_memcpy(&u, &h2, 4);
    return u;
}

// split x -> hi + lo bf16 via packed cvt
__device__ __forceinline__ void split_pack8(float4 a, float4 b, bf16x8& hi, bf16x8& lo) {
    float v[8] = {a.x, a.y, a.z, a.w, b.x, b.y, b.z, b.w};
    unsigned hp[4], lp[4];
#pragma unroll
    for (int i = 0; i < 4; ++i) {
        float x0 = v[2 * i], x1 = v[2 * i + 1];
        unsigned hb = cvt_pk_bf16(x0, x1);
        hp[i] = hb;
        float r0 = x0 - __builtin_bit_cast(float, hb << 16);
        float r1 = x1 - __builtin_bit_cast(float, hb & 0xffff0000u);
        lp[i] = cvt_pk_bf16(r0, r1);
    }
    hi = __builtin_bit_cast(bf16x8, (uint4){hp[0], hp[1], hp[2], hp[3]});
    lo = __builtin_bit_cast(bf16x8, (uint4){lp[0], lp[1], lp[2], lp[3]});
}

__device__ __forceinline__ floatx4 mfma3(bf16x8 Ah, bf16x8 Al, bf16x8 Wh, bf16x8 Wl,
                                         floatx4 acc) {
    acc = __builtin_amdgcn_mfma_f32_16x16x32_bf16(Ah, Wh, acc, 0, 0, 0);
    acc = __builtin_amdgcn_mfma_f32_16x16x32_bf16(Al, Wh, acc, 0, 0, 0);
    acc = __builtin_amdgcn_mfma_f32_16x16x32_bf16(Ah, Wl, acc, 0, 0, 0);
    return acc;
}

// ---- setup: pack 4 weight matrices into B-fragment order, hi/lo split ----
__global__ void pack_weights(const float* __restrict__ W0u, const float* __restrict__ W0i,
                             const float* __restrict__ W1u, const float* __restrict__ W1i,
                             short* __restrict__ pk) {
    const float* Ws[4] = {W0u, W0i, W1u, W1i};
    const int w = blockIdx.x;
    const int wv = threadIdx.x >> 6, lane = threadIdx.x & 63;
    const int quad = lane >> 4, m16 = lane & 15;
    const int nt = wv;
    const float* W = Ws[w];
#pragma unroll
    for (int ks = 0; ks < 2; ++ks) {
        bf16x8 fh, fl;
#pragma unroll
        for (int j = 0; j < 8; ++j) {
            float x = W[(ks * 32 + quad * 8 + j) * 64 + nt * 16 + m16];
            short h = f2bf(x);
            fh[j] = h;
            fl[j] = f2bf(x - bf2f_s(h));
        }
        long base = (long)(((w * 4 + nt) * 2 + ks) * 2) * 64 + lane;
        ((bf16x8*)pk)[base] = fh;
        ((bf16x8*)pk)[base + 64] = fl;
    }
}

__global__ __launch_bounds__(256, 4)
void disenhan_mfma(const float* __restrict__ user_table,
                   const float* __restrict__ item_table,
                   const bf16x8* __restrict__ pk,
                   const int* __restrict__ uidx0, const int* __restrict__ uidx1,
                   const int* __restrict__ uidx2,
                   const int* __restrict__ iidx0, const int* __restrict__ iidx1,
                   const int* __restrict__ iidx2,
                   float* __restrict__ out, int B)
{
    constexpr float SCALE = 0.35355339059327373f;  // 1/sqrt(8)
    const int b = blockIdx.x, branch = blockIdx.y;
    const int tid = threadIdx.x;
    const int wv = tid >> 6, lane = tid & 63;
    const int quad = lane >> 4;   // MFMA k-block selector
    const int m16  = lane & 15;   // MFMA row (A) / col (B,D) selector
    const int rr   = lane >> 4;   // routing: row group (rows 4rr..4rr+3)
    const int j4   = lane & 15;   // routing: col group (cols 4j4..4j4+3)

    // matrix ids in pk: 0=W0u 1=W0i 2=W1u 3=W1i
    const float *tab0, *tab1;
    const int *idx0, *idx1, *idx2;
    int w1c_id, w1n_id, w0n_id;
    if (branch == 0) { tab0 = user_table; tab1 = item_table;
                       idx0 = uidx0; idx1 = uidx1; idx2 = uidx2;
                       w1c_id = 3; w1n_id = 2; w0n_id = 1; }
    else             { tab0 = item_table; tab1 = user_table;
                       idx0 = iidx0; idx1 = iidx1; idx2 = iidx2;
                       w1c_id = 2; w1n_id = 3; w0n_id = 0; }

    __shared__ float sN[4][16 * 68];  // per-wave nh tile (fp32, pitch 68)
    __shared__ float sC[16 * 68];     // hid (= c), pitch 68
    __shared__ float sH[16 * 68];     // h1 (written once per slot at the end)
    __shared__ float sE0[64];         // layer-0 center (e0)

    // e0 prefetch (consumed by wave 0 at the end; loaded by all, uniform)
    const float v0 = tab0[(long)idx0[b] * 64 + lane];

    // ---- B-fragment loader: 16 coalesced 16B loads from the packed buffer ----
    bf16x8 wfh[4][2], wfl[4][2];
    auto load_wfrag = [&](int w) {
#pragma unroll
        for (int nt = 0; nt < 4; ++nt)
#pragma unroll
            for (int ks = 0; ks < 2; ++ks) {
                long base = (long)(((w * 4 + nt) * 2 + ks) * 2) * 64 + lane;
                wfh[nt][ks] = pk[base];
                wfl[nt][ks] = pk[base + 64];
            }
    };

    // ---- register-resident routing: 3 iterations on one s-slot ----
    auto routing_reg = [&](const float* __restrict__ Nw, float4 c4, bool relu_last)
        -> float4 {
        float4 h4 = c4;   // iter-0 htmp = hid
#pragma unroll
        for (int it = 0; it < 3; ++it) {
            float4 Nv[4];
#pragma unroll
            for (int t = 0; t < 4; ++t)
                Nv[t] = *(const float4*)&Nw[(4 * rr + t) * 68 + 4 * j4];
            // logits e[4rr+t][k2]: dot over this lane's 4 cols + pair lane's 4
            float pp[4];
#pragma unroll
            for (int t = 0; t < 4; ++t) {
                float d = h4.x * Nv[t].x + h4.y * Nv[t].y +
                          h4.z * Nv[t].z + h4.w * Nv[t].w;
                d += __shfl_xor(d, 1);        // + other half of the octet
                pp[t] = d * SCALE;
            }
            // softmax over n (16 rows): in-reg over t, shfl over rr
            float m = fmaxf(fmaxf(pp[0], pp[1]), fmaxf(pp[2], pp[3]));
            m = fmaxf(m, __shfl_xor(m, 16));
            m = fmaxf(m, __shfl_xor(m, 32));
            float e0 = __expf(pp[0] - m), e1 = __expf(pp[1] - m);
            float e2 = __expf(pp[2] - m), e3 = __expf(pp[3] - m);
            float sm = (e0 + e1) + (e2 + e3);
            sm += __shfl_xor(sm, 16);
            sm += __shfl_xor(sm, 32);
            float inv = 1.0f / sm;
            float a0 = e0 * inv, a1 = e1 * inv, a2 = e2 * inv, a3 = e3 * inv;
            // z[4j4..] partial over rows 4rr..4rr+3, then reduce over rr
            float4 z;
            z.x = a0 * Nv[0].x; z.y = a0 * Nv[0].y; z.z = a0 * Nv[0].z; z.w = a0 * Nv[0].w;
            z.x = fmaf(a1, Nv[1].x, z.x); z.y = fmaf(a1, Nv[1].y, z.y);
            z.z = fmaf(a1, Nv[1].z, z.z); z.w = fmaf(a1, Nv[1].w, z.w);
            z.x = fmaf(a2, Nv[2].x, z.x); z.y = fmaf(a2, Nv[2].y, z.y);
            z.z = fmaf(a2, Nv[2].z, z.z); z.w = fmaf(a2, Nv[2].w, z.w);
            z.x = fmaf(a3, Nv[3].x, z.x); z.y = fmaf(a3, Nv[3].y, z.y);
            z.z = fmaf(a3, Nv[3].z, z.z); z.w = fmaf(a3, Nv[3].w, z.w);
            z.x += __shfl_xor(z.x, 16); z.y += __shfl_xor(z.y, 16);
            z.z += __shfl_xor(z.z, 16); z.w += __shfl_xor(z.w, 16);
            z.x += __shfl_xor(z.x, 32); z.y += __shfl_xor(z.y, 32);
            z.z += __shfl_xor(z.z, 32); z.w += __shfl_xor(z.w, 32);
            h4.x = c4.x + z.x; h4.y = c4.y + z.y;
            h4.z = c4.z + z.z; h4.w = c4.w + z.w;
            if (relu_last && it == 2) {
                h4.x = fmaxf(h4.x, 0.f); h4.y = fmaxf(h4.y, 0.f);
                h4.z = fmaxf(h4.z, 0.f); h4.w = fmaxf(h4.w, 0.f);
            }
        }
        return h4;
    };

    // ---- 16x64 tile matmul into one sN tile (24 MFMAs) ----
    auto matmul_tile = [&](float4 f0, float4 f1, float4 f2, float4 f3,
                           float* __restrict__ Nw) {
        bf16x8 A0h, A0l, A1h, A1l;
        split_pack8(f0, f1, A0h, A0l);
        split_pack8(f2, f3, A1h, A1l);
        floatx4 acc[4];
#pragma unroll
        for (int nt = 0; nt < 4; ++nt) {
            acc[nt] = (floatx4){0.f, 0.f, 0.f, 0.f};
            acc[nt] = mfma3(A0h, A0l, wfh[nt][0], wfl[nt][0], acc[nt]);
            acc[nt] = mfma3(A1h, A1l, wfh[nt][1], wfl[nt][1], acc[nt]);
        }
#pragma unroll
        for (int nt = 0; nt < 4; ++nt)
#pragma unroll
            for (int rg = 0; rg < 4; ++rg)
                Nw[(quad * 4 + rg) * 68 + nt * 16 + m16] = acc[nt][rg];
    };

    // ---- issue long-latency gathers early ----
    const long g1 = (long)idx1[b * 16 + m16] * 64;
    const float* p1 = &tab1[g1 + quad * 8];
    float4 e1a = *(const float4*)p1;
    float4 e1b = *(const float4*)(p1 + 4);
    float4 e1c = *(const float4*)(p1 + 32);
    float4 e1d = *(const float4*)(p1 + 36);
    int gidx[4];
#pragma unroll
    for (int q = 0; q < 4; ++q)
        gidx[q] = idx2[b * 256 + (wv * 4 + q) * 16 + m16];

    // ================= layer-1 pre-encode: hid = e1 @ W1c =================
    load_wfrag(w1c_id);
    {
        bf16x8 A0h, A0l, A1h, A1l;
        split_pack8(e1a, e1b, A0h, A0l);
        split_pack8(e1c, e1d, A1h, A1l);
        floatx4 hacc[4];
#pragma unroll
        for (int nt = 0; nt < 4; ++nt) {
            hacc[nt] = (floatx4){0.f, 0.f, 0.f, 0.f};
            hacc[nt] = mfma3(A0h, A0l, wfh[nt][0], wfl[nt][0], hacc[nt]);
            hacc[nt] = mfma3(A1h, A1l, wfh[nt][1], wfl[nt][1], hacc[nt]);
        }
        // D: row = quad*4+reg, col = nt*16+m16. Wave w keeps rows w*4..w*4+3
        // (quad==wv lanes) — exactly its own routing slots. Only sC needed.
        if (quad == wv) {
#pragma unroll
            for (int nt = 0; nt < 4; ++nt)
#pragma unroll
                for (int rg = 0; rg < 4; ++rg)
                    sC[(quad * 4 + rg) * 68 + nt * 16 + m16] = hacc[nt][rg];
        }
    }
    __builtin_amdgcn_wave_barrier();

    // ================= layer-1 main: 4 s-slots per wave =================
    float4 f0, f1, f2, f3;
    {
        const float* p = &tab0[(long)gidx[0] * 64 + quad * 8];
        f0 = *(const float4*)p;        f1 = *(const float4*)(p + 4);
        f2 = *(const float4*)(p + 32); f3 = *(const float4*)(p + 36);
    }
    load_wfrag(w1n_id);
#pragma unroll
    for (int q = 0; q < 4; ++q) {
        const int s = wv * 4 + q;
        matmul_tile(f0, f1, f2, f3, sN[wv]);
        if (q < 3) {  // prefetch next slot's A rows; consumed next iteration
            const float* p = &tab0[(long)gidx[q + 1] * 64 + quad * 8];
            f0 = *(const float4*)p;        f1 = *(const float4*)(p + 4);
            f2 = *(const float4*)(p + 32); f3 = *(const float4*)(p + 36);
        }
        __builtin_amdgcn_wave_barrier();
        float4 c4 = *(const float4*)&sC[s * 68 + 4 * j4];
        float4 h4 = routing_reg(sN[wv], c4, true);
        if (rr == 0)
            *(float4*)&sH[s * 68 + 4 * j4] = h4;   // h1 row s
        __builtin_amdgcn_wave_barrier();           // sN reads done before next matmul
    }

    // ================= layer-0 =================
    __syncthreads();   // the only block barrier: all h1 rows visible
    if (wv == 0) {
        load_wfrag(w0n_id);
        sE0[lane] = v0;
        bf16x8 A0h, A0l, A1h, A1l;
        {
            const float* hp = &sH[m16 * 68];
            split_pack8(*(const float4*)&hp[quad * 8],
                        *(const float4*)&hp[quad * 8 + 4], A0h, A0l);
            split_pack8(*(const float4*)&hp[32 + quad * 8],
                        *(const float4*)&hp[32 + quad * 8 + 4], A1h, A1l);
        }
        floatx4 acc[4];
#pragma unroll
        for (int nt = 0; nt < 4; ++nt) {
            acc[nt] = (floatx4){0.f, 0.f, 0.f, 0.f};
            acc[nt] = mfma3(A0h, A0l, wfh[nt][0], wfl[nt][0], acc[nt]);
            acc[nt] = mfma3(A1h, A1l, wfh[nt][1], wfl[nt][1], acc[nt]);
        }
#pragma unroll
        for (int nt = 0; nt < 4; ++nt)
#pragma unroll
            for (int rg = 0; rg < 4; ++rg)
                sN[0][(quad * 4 + rg) * 68 + nt * 16 + m16] = acc[nt][rg];
        __builtin_amdgcn_wave_barrier();
        float4 c4 = *(const float4*)&sE0[4 * j4];
        float4 h4 = routing_reg(sN[0], c4, false);
        if (rr == 0)
            *(float4*)&out[((long)branch * B + b) * 64 + 4 * j4] = h4;
    }
}

extern "C" void kernel_launch(void* const* d_in, const int* in_sizes, int n_in,
                              void* d_out, int out_size, void* d_ws, size_t ws_size,
                              hipStream_t stream) {
    const float* user_table = (const float*)d_in[0];
    const float* item_table = (const float*)d_in[1];
    const float* W0u = (const float*)d_in[2];
    const float* W0i = (const float*)d_in[3];
    const float* W1u = (const float*)d_in[4];
    const float* W1i = (const float*)d_in[5];
    const int* uidx0 = (const int*)d_in[6];
    const int* uidx1 = (const int*)d_in[7];
    const int* uidx2 = (const int*)d_in[8];
    const int* iidx0 = (const int*)d_in[9];
    const int* iidx1 = (const int*)d_in[10];
    const int* iidx2 = (const int*)d_in[11];
    float* out = (float*)d_out;
    short* pk = (short*)d_ws;   // 4 matrices * 16 frags * 64 lanes * 16B = 64 KB

    const int B = in_sizes[6];  // 2048
    hipLaunchKernelGGL(pack_weights, dim3(4), dim3(256), 0, stream,
                       W0u, W0i, W1u, W1i, pk);
    dim3 grid(B, 2), block(NTH);
    hipLaunchKernelGGL(disenhan_mfma, grid, block, 0, stream,
                       user_table, item_table, (const bf16x8*)pk,
                       uidx0, uidx1, uidx2, iidx0, iidx1, iidx2, out, B);
}

// Round 13
// 174.647 us; speedup vs baseline: 1.3467x; 1.0085x over previous
//
#include <hip/hip_runtime.h>
#include <hip/hip_bf16.h>

// DisenHAN fused, MFMA split-bf16 edition, v9 (gfx950).
// v9: TWO batch elements per block (grid (B/2, 2)). Round-12 analysis: each
// wave is ~87% latency-stalled and occupancy is hard-capped at 4 waves/EU by
// the 128-reg footprint (64 VGPR + ~64 AGPR-side frags/accs; (256,5) spills).
// So cut per-block redundant work instead:
//  - the 3 load_wfrag phases (48x16B L2 loads/lane) now serve 2 batches
//  - layer-0 tail runs on waves 0 AND 1 (one batch each; was 1 wave + 3 idle)
//  - block count halves -> half the start/drain overhead
// Batches are processed strictly sequentially inside each phase so peak
// register pressure stays at v8's level (+~3 VGPRs). LDS 26.6->35.3KB
// (sC/sH 16->32 rows); 4 blocks x 35.3 = 141KB < 160KB -> occupancy intact.
// v6/v8 recap: register-resident routing (rr=lane>>4 rows, j4=lane&15 cols),
// one b128 pass/iter feeds logits AND z, softmax+z via shfl_xor, htmp in
// registers; separate 4-block pack kernel -> pk fragments in d_ws; cvt_pk
// hi/lo split; launch_bounds(256,4) (cap 128 = measured footprint; (256,5)
// and (256,6) spill — do not raise).
// 3-pass split-bf16 MFMA: A_hi*W_hi + A_lo*W_hi + A_hi*W_lo (~fp32 accuracy).
// T=1 collapses hete-attention: beta==1, wp==1 forever.

#define NTH 256

typedef __attribute__((ext_vector_type(8))) short bf16x8;   // 8 bf16 (4 VGPRs)
typedef __attribute__((ext_vector_type(4))) float floatx4;

__device__ __forceinline__ short f2bf(float f) {            // RNE fp32->bf16 (pack kernel)
    unsigned u = __builtin_bit_cast(unsigned, f);
    unsigned r = u + 0x7fffu + ((u >> 16) & 1u);
    return (short)(r >> 16);
}
__device__ __forceinline__ float bf2f_s(short h) {
    return __builtin_bit_cast(float, (unsigned)((unsigned short)h) << 16);
}

// pack two fp32 -> one dword of two bf16 (v_cvt_pk_bf16_f32)
__device__ __forceinline__ unsigned cvt_pk_bf16(float x0, float x1) {
    __hip_bfloat162 h2 = __float22bfloat162_rn(make_float2(x0, x1));
    unsigned u;
    __builtin_memcpy(&u, &h2, 4);
    return u;
}

// split x -> hi + lo bf16 via packed cvt
__device__ __forceinline__ void split_pack8(float4 a, float4 b, bf16x8& hi, bf16x8& lo) {
    float v[8] = {a.x, a.y, a.z, a.w, b.x, b.y, b.z, b.w};
    unsigned hp[4], lp[4];
#pragma unroll
    for (int i = 0; i < 4; ++i) {
        float x0 = v[2 * i], x1 = v[2 * i + 1];
        unsigned hb = cvt_pk_bf16(x0, x1);
        hp[i] = hb;
        float r0 = x0 - __builtin_bit_cast(float, hb << 16);
        float r1 = x1 - __builtin_bit_cast(float, hb & 0xffff0000u);
        lp[i] = cvt_pk_bf16(r0, r1);
    }
    hi = __builtin_bit_cast(bf16x8, (uint4){hp[0], hp[1], hp[2], hp[3]});
    lo = __builtin_bit_cast(bf16x8, (uint4){lp[0], lp[1], lp[2], lp[3]});
}

__device__ __forceinline__ floatx4 mfma3(bf16x8 Ah, bf16x8 Al, bf16x8 Wh, bf16x8 Wl,
                                         floatx4 acc) {
    acc = __builtin_amdgcn_mfma_f32_16x16x32_bf16(Ah, Wh, acc, 0, 0, 0);
    acc = __builtin_amdgcn_mfma_f32_16x16x32_bf16(Al, Wh, acc, 0, 0, 0);
    acc = __builtin_amdgcn_mfma_f32_16x16x32_bf16(Ah, Wl, acc, 0, 0, 0);
    return acc;
}

// ---- setup: pack 4 weight matrices into B-fragment order, hi/lo split ----
__global__ void pack_weights(const float* __restrict__ W0u, const float* __restrict__ W0i,
                             const float* __restrict__ W1u, const float* __restrict__ W1i,
                             short* __restrict__ pk) {
    const float* Ws[4] = {W0u, W0i, W1u, W1i};
    const int w = blockIdx.x;
    const int wv = threadIdx.x >> 6, lane = threadIdx.x & 63;
    const int quad = lane >> 4, m16 = lane & 15;
    const int nt = wv;
    const float* W = Ws[w];
#pragma unroll
    for (int ks = 0; ks < 2; ++ks) {
        bf16x8 fh, fl;
#pragma unroll
        for (int j = 0; j < 8; ++j) {
            float x = W[(ks * 32 + quad * 8 + j) * 64 + nt * 16 + m16];
            short h = f2bf(x);
            fh[j] = h;
            fl[j] = f2bf(x - bf2f_s(h));
        }
        long base = (long)(((w * 4 + nt) * 2 + ks) * 2) * 64 + lane;
        ((bf16x8*)pk)[base] = fh;
        ((bf16x8*)pk)[base + 64] = fl;
    }
}

__global__ __launch_bounds__(256, 4)
void disenhan_mfma(const float* __restrict__ user_table,
                   const float* __restrict__ item_table,
                   const bf16x8* __restrict__ pk,
                   const int* __restrict__ uidx0, const int* __restrict__ uidx1,
                   const int* __restrict__ uidx2,
                   const int* __restrict__ iidx0, const int* __restrict__ iidx1,
                   const int* __restrict__ iidx2,
                   float* __restrict__ out, int B)
{
    constexpr float SCALE = 0.35355339059327373f;  // 1/sqrt(8)
    const int branch = blockIdx.y;
    const int tid = threadIdx.x;
    const int wv = tid >> 6, lane = tid & 63;
    const int quad = lane >> 4;   // MFMA k-block selector
    const int m16  = lane & 15;   // MFMA row (A) / col (B,D) selector
    const int rr   = lane >> 4;   // routing: row group (rows 4rr..4rr+3)
    const int j4   = lane & 15;   // routing: col group (cols 4j4..4j4+3)

    const int b0 = blockIdx.x * 2;
    int b1 = b0 + 1;
    if (b1 >= B) b1 = b0;         // odd-B guard: duplicate work, benign

    // matrix ids in pk: 0=W0u 1=W0i 2=W1u 3=W1i
    const float *tab0, *tab1;
    const int *idx0, *idx1, *idx2;
    int w1c_id, w1n_id, w0n_id;
    if (branch == 0) { tab0 = user_table; tab1 = item_table;
                       idx0 = uidx0; idx1 = uidx1; idx2 = uidx2;
                       w1c_id = 3; w1n_id = 2; w0n_id = 1; }
    else             { tab0 = item_table; tab1 = user_table;
                       idx0 = iidx0; idx1 = iidx1; idx2 = iidx2;
                       w1c_id = 2; w1n_id = 3; w0n_id = 0; }

    __shared__ float sN[4][16 * 68];  // per-wave nh tile (fp32, pitch 68)
    __shared__ float sC[32 * 68];     // hid for both batches (rows bb*16+s)
    __shared__ float sH[32 * 68];     // h1 for both batches
    __shared__ float sE0[2][64];      // layer-0 centers (e0) per batch

    // e0 prefetch (consumed by waves 0/1 at the end; loaded by all, uniform)
    const float v00 = tab0[(long)idx0[b0] * 64 + lane];
    const float v01 = tab0[(long)idx0[b1] * 64 + lane];

    // ---- B-fragment loader: 16 coalesced 16B loads from the packed buffer ----
    bf16x8 wfh[4][2], wfl[4][2];
    auto load_wfrag = [&](int w) {
#pragma unroll
        for (int nt = 0; nt < 4; ++nt)
#pragma unroll
            for (int ks = 0; ks < 2; ++ks) {
                long base = (long)(((w * 4 + nt) * 2 + ks) * 2) * 64 + lane;
                wfh[nt][ks] = pk[base];
                wfl[nt][ks] = pk[base + 64];
            }
    };

    // ---- register-resident routing: 3 iterations on one s-slot ----
    auto routing_reg = [&](const float* __restrict__ Nw, float4 c4, bool relu_last)
        -> float4 {
        float4 h4 = c4;   // iter-0 htmp = hid
#pragma unroll
        for (int it = 0; it < 3; ++it) {
            float4 Nv[4];
#pragma unroll
            for (int t = 0; t < 4; ++t)
                Nv[t] = *(const float4*)&Nw[(4 * rr + t) * 68 + 4 * j4];
            // logits e[4rr+t][k2]: dot over this lane's 4 cols + pair lane's 4
            float pp[4];
#pragma unroll
            for (int t = 0; t < 4; ++t) {
                float d = h4.x * Nv[t].x + h4.y * Nv[t].y +
                          h4.z * Nv[t].z + h4.w * Nv[t].w;
                d += __shfl_xor(d, 1);        // + other half of the octet
                pp[t] = d * SCALE;
            }
            // softmax over n (16 rows): in-reg over t, shfl over rr
            float m = fmaxf(fmaxf(pp[0], pp[1]), fmaxf(pp[2], pp[3]));
            m = fmaxf(m, __shfl_xor(m, 16));
            m = fmaxf(m, __shfl_xor(m, 32));
            float e0 = __expf(pp[0] - m), e1 = __expf(pp[1] - m);
            float e2 = __expf(pp[2] - m), e3 = __expf(pp[3] - m);
            float sm = (e0 + e1) + (e2 + e3);
            sm += __shfl_xor(sm, 16);
            sm += __shfl_xor(sm, 32);
            float inv = 1.0f / sm;
            float a0 = e0 * inv, a1 = e1 * inv, a2 = e2 * inv, a3 = e3 * inv;
            // z[4j4..] partial over rows 4rr..4rr+3, then reduce over rr
            float4 z;
            z.x = a0 * Nv[0].x; z.y = a0 * Nv[0].y; z.z = a0 * Nv[0].z; z.w = a0 * Nv[0].w;
            z.x = fmaf(a1, Nv[1].x, z.x); z.y = fmaf(a1, Nv[1].y, z.y);
            z.z = fmaf(a1, Nv[1].z, z.z); z.w = fmaf(a1, Nv[1].w, z.w);
            z.x = fmaf(a2, Nv[2].x, z.x); z.y = fmaf(a2, Nv[2].y, z.y);
            z.z = fmaf(a2, Nv[2].z, z.z); z.w = fmaf(a2, Nv[2].w, z.w);
            z.x = fmaf(a3, Nv[3].x, z.x); z.y = fmaf(a3, Nv[3].y, z.y);
            z.z = fmaf(a3, Nv[3].z, z.z); z.w = fmaf(a3, Nv[3].w, z.w);
            z.x += __shfl_xor(z.x, 16); z.y += __shfl_xor(z.y, 16);
            z.z += __shfl_xor(z.z, 16); z.w += __shfl_xor(z.w, 16);
            z.x += __shfl_xor(z.x, 32); z.y += __shfl_xor(z.y, 32);
            z.z += __shfl_xor(z.z, 32); z.w += __shfl_xor(z.w, 32);
            h4.x = c4.x + z.x; h4.y = c4.y + z.y;
            h4.z = c4.z + z.z; h4.w = c4.w + z.w;
            if (relu_last && it == 2) {
                h4.x = fmaxf(h4.x, 0.f); h4.y = fmaxf(h4.y, 0.f);
                h4.z = fmaxf(h4.z, 0.f); h4.w = fmaxf(h4.w, 0.f);
            }
        }
        return h4;
    };

    // ---- 16x64 tile matmul into one sN tile (24 MFMAs) ----
    auto matmul_tile = [&](float4 f0, float4 f1, float4 f2, float4 f3,
                           float* __restrict__ Nw) {
        bf16x8 A0h, A0l, A1h, A1l;
        split_pack8(f0, f1, A0h, A0l);
        split_pack8(f2, f3, A1h, A1l);
        floatx4 acc[4];
#pragma unroll
        for (int nt = 0; nt < 4; ++nt) {
            acc[nt] = (floatx4){0.f, 0.f, 0.f, 0.f};
            acc[nt] = mfma3(A0h, A0l, wfh[nt][0], wfl[nt][0], acc[nt]);
            acc[nt] = mfma3(A1h, A1l, wfh[nt][1], wfl[nt][1], acc[nt]);
        }
#pragma unroll
        for (int nt = 0; nt < 4; ++nt)
#pragma unroll
            for (int rg = 0; rg < 4; ++rg)
                Nw[(quad * 4 + rg) * 68 + nt * 16 + m16] = acc[nt][rg];
    };

    // ================= layer-1 pre-encode: hid = e1 @ W1c (both batches) ======
    load_wfrag(w1c_id);
#pragma unroll
    for (int bb = 0; bb < 2; ++bb) {
        const int bcur = bb ? b1 : b0;
        const float* p1 = &tab1[(long)idx1[bcur * 16 + m16] * 64 + quad * 8];
        float4 e1a = *(const float4*)p1;
        float4 e1b = *(const float4*)(p1 + 4);
        float4 e1c = *(const float4*)(p1 + 32);
        float4 e1d = *(const float4*)(p1 + 36);
        bf16x8 A0h, A0l, A1h, A1l;
        split_pack8(e1a, e1b, A0h, A0l);
        split_pack8(e1c, e1d, A1h, A1l);
        floatx4 hacc[4];
#pragma unroll
        for (int nt = 0; nt < 4; ++nt) {
            hacc[nt] = (floatx4){0.f, 0.f, 0.f, 0.f};
            hacc[nt] = mfma3(A0h, A0l, wfh[nt][0], wfl[nt][0], hacc[nt]);
            hacc[nt] = mfma3(A1h, A1l, wfh[nt][1], wfl[nt][1], hacc[nt]);
        }
        // D: row = quad*4+reg, col = nt*16+m16. Wave w keeps rows w*4..w*4+3
        // (quad==wv lanes) — exactly its own routing slots. Only sC needed.
        if (quad == wv) {
#pragma unroll
            for (int nt = 0; nt < 4; ++nt)
#pragma unroll
                for (int rg = 0; rg < 4; ++rg)
                    sC[(bb * 16 + quad * 4 + rg) * 68 + nt * 16 + m16] = hacc[nt][rg];
        }
    }
    __builtin_amdgcn_wave_barrier();

    // ================= layer-1 main: 4 s-slots per wave per batch =============
    load_wfrag(w1n_id);
#pragma unroll
    for (int bb = 0; bb < 2; ++bb) {
        const int bcur = bb ? b1 : b0;
        int gidx[4];
#pragma unroll
        for (int q = 0; q < 4; ++q)
            gidx[q] = idx2[bcur * 256 + (wv * 4 + q) * 16 + m16];
        float4 f0, f1, f2, f3;
        {
            const float* p = &tab0[(long)gidx[0] * 64 + quad * 8];
            f0 = *(const float4*)p;        f1 = *(const float4*)(p + 4);
            f2 = *(const float4*)(p + 32); f3 = *(const float4*)(p + 36);
        }
#pragma unroll
        for (int q = 0; q < 4; ++q) {
            const int srow = bb * 16 + wv * 4 + q;
            matmul_tile(f0, f1, f2, f3, sN[wv]);
            if (q < 3) {  // prefetch next slot's A rows; consumed next iteration
                const float* p = &tab0[(long)gidx[q + 1] * 64 + quad * 8];
                f0 = *(const float4*)p;        f1 = *(const float4*)(p + 4);
                f2 = *(const float4*)(p + 32); f3 = *(const float4*)(p + 36);
            }
            __builtin_amdgcn_wave_barrier();
            float4 c4 = *(const float4*)&sC[srow * 68 + 4 * j4];
            float4 h4 = routing_reg(sN[wv], c4, true);
            if (rr == 0)
                *(float4*)&sH[srow * 68 + 4 * j4] = h4;   // h1 row
            __builtin_amdgcn_wave_barrier();   // sN reads done before next matmul
        }
    }

    // ================= layer-0: wave 0 -> b0, wave 1 -> b1 ====================
    __syncthreads();   // the only block barrier: all h1 rows visible
    if (wv < 2) {
        const int bcur = wv ? b1 : b0;
        load_wfrag(w0n_id);
        sE0[wv][lane] = wv ? v01 : v00;
        bf16x8 A0h, A0l, A1h, A1l;
        {
            const float* hp = &sH[(wv * 16 + m16) * 68];
            split_pack8(*(const float4*)&hp[quad * 8],
                        *(const float4*)&hp[quad * 8 + 4], A0h, A0l);
            split_pack8(*(const float4*)&hp[32 + quad * 8],
                        *(const float4*)&hp[32 + quad * 8 + 4], A1h, A1l);
        }
        floatx4 acc[4];
#pragma unroll
        for (int nt = 0; nt < 4; ++nt) {
            acc[nt] = (floatx4){0.f, 0.f, 0.f, 0.f};
            acc[nt] = mfma3(A0h, A0l, wfh[nt][0], wfl[nt][0], acc[nt]);
            acc[nt] = mfma3(A1h, A1l, wfh[nt][1], wfl[nt][1], acc[nt]);
        }
#pragma unroll
        for (int nt = 0; nt < 4; ++nt)
#pragma unroll
            for (int rg = 0; rg < 4; ++rg)
                sN[wv][(quad * 4 + rg) * 68 + nt * 16 + m16] = acc[nt][rg];
        __builtin_amdgcn_wave_barrier();
        float4 c4 = *(const float4*)&sE0[wv][4 * j4];
        float4 h4 = routing_reg(sN[wv], c4, false);
        if (rr == 0)
            *(float4*)&out[((long)branch * B + bcur) * 64 + 4 * j4] = h4;
    }
}

extern "C" void kernel_launch(void* const* d_in, const int* in_sizes, int n_in,
                              void* d_out, int out_size, void* d_ws, size_t ws_size,
                              hipStream_t stream) {
    const float* user_table = (const float*)d_in[0];
    const float* item_table = (const float*)d_in[1];
    const float* W0u = (const float*)d_in[2];
    const float* W0i = (const float*)d_in[3];
    const float* W1u = (const float*)d_in[4];
    const float* W1i = (const float*)d_in[5];
    const int* uidx0 = (const int*)d_in[6];
    const int* uidx1 = (const int*)d_in[7];
    const int* uidx2 = (const int*)d_in[8];
    const int* iidx0 = (const int*)d_in[9];
    const int* iidx1 = (const int*)d_in[10];
    const int* iidx2 = (const int*)d_in[11];
    float* out = (float*)d_out;
    short* pk = (short*)d_ws;   // 4 matrices * 16 frags * 64 lanes * 16B = 64 KB

    const int B = in_sizes[6];  // 2048
    hipLaunchKernelGGL(pack_weights, dim3(4), dim3(256), 0, stream,
                       W0u, W0i, W1u, W1i, pk);
    dim3 grid((B + 1) / 2, 2), block(NTH);
    hipLaunchKernelGGL(disenhan_mfma, grid, block, 0, stream,
                       user_table, item_table, (const bf16x8*)pk,
                       uidx0, uidx1, uidx2, iidx0, iidx1, iidx2, out, B);
}

// Round 14
// 163.814 us; speedup vs baseline: 1.4358x; 1.0661x over previous
//
#include <hip/hip_runtime.h>
#include <hip/hip_bf16.h>
#include <hip/hip_fp16.h>

// DisenHAN fused, single-pass FP16 MFMA edition, v10 (gfx950).
// v10: replace the 3-pass split-bf16 emulation with ONE fp16 MFMA pass.
// Rationale: round-3 measured bf16-single absmax = 0.219 (fail at 0.18125);
// fp16 has 3 more mantissa bits -> predicted ~0.027 + existing 0.031 floor
// = ~0.05, comfortably under threshold. |values| <= ~10 << fp16 max.
//  - MFMA per 16x64 tile: 24 -> 8 (mfma_f32_16x16x32_f16)
//  - hi/lo split conversions -> plain RNE fp32->fp16 casts
//  - W-fragment file halves (32 VGPRs); pk buffer 64KB -> 32KB
//  - Nv tile loads hoisted out of the 3-iteration routing loop (sN invariant)
// Structure retained from v9: 2 batch elements per block (grid (B/2,2)),
// register-resident routing (rr=lane>>4 rows, j4=lane&15 cols; softmax+z via
// shfl_xor; htmp in registers; conflicts 1.18M), separate 4-block pack kernel
// -> pk fragments in d_ws, early gathers, per-slot prefetch, layer-0 tail on
// waves 0/1 (one batch each), launch_bounds(256,4) (cap 128; (256,5) spilled
// twice — do not raise without re-measuring footprint).
// T=1 collapses hete-attention: beta==1, wp==1 forever.

#define NTH 256

typedef __attribute__((ext_vector_type(8))) _Float16 half8;  // 8 fp16 (4 VGPRs)
typedef __attribute__((ext_vector_type(4))) float floatx4;

__device__ __forceinline__ half8 pack8_f16(float4 a, float4 b) {
    half8 r;
    r[0] = (_Float16)a.x; r[1] = (_Float16)a.y;
    r[2] = (_Float16)a.z; r[3] = (_Float16)a.w;
    r[4] = (_Float16)b.x; r[5] = (_Float16)b.y;
    r[6] = (_Float16)b.z; r[7] = (_Float16)b.w;
    return r;
}

// ---- setup: pack 4 weight matrices into fp16 B-fragment order ----
// layout: frag[ (w*4+nt)*2+ks ][ lane ] = 8 fp16 (16B), coalesced.
__global__ void pack_weights(const float* __restrict__ W0u, const float* __restrict__ W0i,
                             const float* __restrict__ W1u, const float* __restrict__ W1i,
                             half8* __restrict__ pk) {
    const float* Ws[4] = {W0u, W0i, W1u, W1i};
    const int w = blockIdx.x;
    const int wv = threadIdx.x >> 6, lane = threadIdx.x & 63;
    const int quad = lane >> 4, m16 = lane & 15;
    const int nt = wv;
    const float* W = Ws[w];
#pragma unroll
    for (int ks = 0; ks < 2; ++ks) {
        half8 f;
#pragma unroll
        for (int j = 0; j < 8; ++j)
            f[j] = (_Float16)W[(ks * 32 + quad * 8 + j) * 64 + nt * 16 + m16];
        pk[(long)(((w * 4 + nt) * 2 + ks)) * 64 + lane] = f;
    }
}

__global__ __launch_bounds__(256, 4)
void disenhan_mfma(const float* __restrict__ user_table,
                   const float* __restrict__ item_table,
                   const half8* __restrict__ pk,
                   const int* __restrict__ uidx0, const int* __restrict__ uidx1,
                   const int* __restrict__ uidx2,
                   const int* __restrict__ iidx0, const int* __restrict__ iidx1,
                   const int* __restrict__ iidx2,
                   float* __restrict__ out, int B)
{
    constexpr float SCALE = 0.35355339059327373f;  // 1/sqrt(8)
    const int branch = blockIdx.y;
    const int tid = threadIdx.x;
    const int wv = tid >> 6, lane = tid & 63;
    const int quad = lane >> 4;   // MFMA k-block selector
    const int m16  = lane & 15;   // MFMA row (A) / col (B,D) selector
    const int rr   = lane >> 4;   // routing: row group (rows 4rr..4rr+3)
    const int j4   = lane & 15;   // routing: col group (cols 4j4..4j4+3)

    const int b0 = blockIdx.x * 2;
    int b1 = b0 + 1;
    if (b1 >= B) b1 = b0;         // odd-B guard: duplicate work, benign

    // matrix ids in pk: 0=W0u 1=W0i 2=W1u 3=W1i
    const float *tab0, *tab1;
    const int *idx0, *idx1, *idx2;
    int w1c_id, w1n_id, w0n_id;
    if (branch == 0) { tab0 = user_table; tab1 = item_table;
                       idx0 = uidx0; idx1 = uidx1; idx2 = uidx2;
                       w1c_id = 3; w1n_id = 2; w0n_id = 1; }
    else             { tab0 = item_table; tab1 = user_table;
                       idx0 = iidx0; idx1 = iidx1; idx2 = iidx2;
                       w1c_id = 2; w1n_id = 3; w0n_id = 0; }

    __shared__ float sN[4][16 * 68];  // per-wave nh tile (fp32, pitch 68)
    __shared__ float sC[32 * 68];     // hid for both batches (rows bb*16+s)
    __shared__ float sH[32 * 68];     // h1 for both batches
    __shared__ float sE0[2][64];      // layer-0 centers (e0) per batch

    // e0 prefetch (consumed by waves 0/1 at the end; loaded by all, uniform)
    const float v00 = tab0[(long)idx0[b0] * 64 + lane];
    const float v01 = tab0[(long)idx0[b1] * 64 + lane];

    // ---- B-fragment loader: 8 coalesced 16B loads from the packed buffer ----
    half8 wf[4][2];
    auto load_wfrag = [&](int w) {
#pragma unroll
        for (int nt = 0; nt < 4; ++nt)
#pragma unroll
            for (int ks = 0; ks < 2; ++ks)
                wf[nt][ks] = pk[(long)(((w * 4 + nt) * 2 + ks)) * 64 + lane];
    };

    // ---- register-resident routing: 3 iterations on one s-slot ----
    // Nv loaded ONCE (sN invariant across iterations), reused for logits and z.
    auto routing_reg = [&](const float* __restrict__ Nw, float4 c4, bool relu_last)
        -> float4 {
        float4 Nv[4];
#pragma unroll
        for (int t = 0; t < 4; ++t)
            Nv[t] = *(const float4*)&Nw[(4 * rr + t) * 68 + 4 * j4];
        float4 h4 = c4;   // iter-0 htmp = hid
#pragma unroll
        for (int it = 0; it < 3; ++it) {
            // logits e[4rr+t][k2]: dot over this lane's 4 cols + pair lane's 4
            float pp[4];
#pragma unroll
            for (int t = 0; t < 4; ++t) {
                float d = h4.x * Nv[t].x + h4.y * Nv[t].y +
                          h4.z * Nv[t].z + h4.w * Nv[t].w;
                d += __shfl_xor(d, 1);        // + other half of the octet
                pp[t] = d * SCALE;
            }
            // softmax over n (16 rows): in-reg over t, shfl over rr
            float m = fmaxf(fmaxf(pp[0], pp[1]), fmaxf(pp[2], pp[3]));
            m = fmaxf(m, __shfl_xor(m, 16));
            m = fmaxf(m, __shfl_xor(m, 32));
            float e0 = __expf(pp[0] - m), e1 = __expf(pp[1] - m);
            float e2 = __expf(pp[2] - m), e3 = __expf(pp[3] - m);
            float sm = (e0 + e1) + (e2 + e3);
            sm += __shfl_xor(sm, 16);
            sm += __shfl_xor(sm, 32);
            float inv = 1.0f / sm;
            float a0 = e0 * inv, a1 = e1 * inv, a2 = e2 * inv, a3 = e3 * inv;
            // z[4j4..] partial over rows 4rr..4rr+3, then reduce over rr
            float4 z;
            z.x = a0 * Nv[0].x; z.y = a0 * Nv[0].y; z.z = a0 * Nv[0].z; z.w = a0 * Nv[0].w;
            z.x = fmaf(a1, Nv[1].x, z.x); z.y = fmaf(a1, Nv[1].y, z.y);
            z.z = fmaf(a1, Nv[1].z, z.z); z.w = fmaf(a1, Nv[1].w, z.w);
            z.x = fmaf(a2, Nv[2].x, z.x); z.y = fmaf(a2, Nv[2].y, z.y);
            z.z = fmaf(a2, Nv[2].z, z.z); z.w = fmaf(a2, Nv[2].w, z.w);
            z.x = fmaf(a3, Nv[3].x, z.x); z.y = fmaf(a3, Nv[3].y, z.y);
            z.z = fmaf(a3, Nv[3].z, z.z); z.w = fmaf(a3, Nv[3].w, z.w);
            z.x += __shfl_xor(z.x, 16); z.y += __shfl_xor(z.y, 16);
            z.z += __shfl_xor(z.z, 16); z.w += __shfl_xor(z.w, 16);
            z.x += __shfl_xor(z.x, 32); z.y += __shfl_xor(z.y, 32);
            z.z += __shfl_xor(z.z, 32); z.w += __shfl_xor(z.w, 32);
            h4.x = c4.x + z.x; h4.y = c4.y + z.y;
            h4.z = c4.z + z.z; h4.w = c4.w + z.w;
            if (relu_last && it == 2) {
                h4.x = fmaxf(h4.x, 0.f); h4.y = fmaxf(h4.y, 0.f);
                h4.z = fmaxf(h4.z, 0.f); h4.w = fmaxf(h4.w, 0.f);
            }
        }
        return h4;
    };

    // ---- 16x64 tile matmul into one sN tile (8 MFMAs) ----
    auto matmul_tile = [&](float4 f0, float4 f1, float4 f2, float4 f3,
                           float* __restrict__ Nw) {
        half8 A0 = pack8_f16(f0, f1);
        half8 A1 = pack8_f16(f2, f3);
        floatx4 acc[4];
#pragma unroll
        for (int nt = 0; nt < 4; ++nt) {
            acc[nt] = (floatx4){0.f, 0.f, 0.f, 0.f};
            acc[nt] = __builtin_amdgcn_mfma_f32_16x16x32_f16(A0, wf[nt][0], acc[nt], 0, 0, 0);
            acc[nt] = __builtin_amdgcn_mfma_f32_16x16x32_f16(A1, wf[nt][1], acc[nt], 0, 0, 0);
        }
#pragma unroll
        for (int nt = 0; nt < 4; ++nt)
#pragma unroll
            for (int rg = 0; rg < 4; ++rg)
                Nw[(quad * 4 + rg) * 68 + nt * 16 + m16] = acc[nt][rg];
    };

    // ================= layer-1 pre-encode: hid = e1 @ W1c (both batches) ======
    load_wfrag(w1c_id);
#pragma unroll
    for (int bb = 0; bb < 2; ++bb) {
        const int bcur = bb ? b1 : b0;
        const float* p1 = &tab1[(long)idx1[bcur * 16 + m16] * 64 + quad * 8];
        float4 e1a = *(const float4*)p1;
        float4 e1b = *(const float4*)(p1 + 4);
        float4 e1c = *(const float4*)(p1 + 32);
        float4 e1d = *(const float4*)(p1 + 36);
        half8 A0 = pack8_f16(e1a, e1b);
        half8 A1 = pack8_f16(e1c, e1d);
        floatx4 hacc[4];
#pragma unroll
        for (int nt = 0; nt < 4; ++nt) {
            hacc[nt] = (floatx4){0.f, 0.f, 0.f, 0.f};
            hacc[nt] = __builtin_amdgcn_mfma_f32_16x16x32_f16(A0, wf[nt][0], hacc[nt], 0, 0, 0);
            hacc[nt] = __builtin_amdgcn_mfma_f32_16x16x32_f16(A1, wf[nt][1], hacc[nt], 0, 0, 0);
        }
        // D: row = quad*4+reg, col = nt*16+m16. Wave w keeps rows w*4..w*4+3
        // (quad==wv lanes) — exactly its own routing slots. Only sC needed.
        if (quad == wv) {
#pragma unroll
            for (int nt = 0; nt < 4; ++nt)
#pragma unroll
                for (int rg = 0; rg < 4; ++rg)
                    sC[(bb * 16 + quad * 4 + rg) * 68 + nt * 16 + m16] = hacc[nt][rg];
        }
    }
    __builtin_amdgcn_wave_barrier();

    // ================= layer-1 main: 4 s-slots per wave per batch =============
    load_wfrag(w1n_id);
#pragma unroll
    for (int bb = 0; bb < 2; ++bb) {
        const int bcur = bb ? b1 : b0;
        int gidx[4];
#pragma unroll
        for (int q = 0; q < 4; ++q)
            gidx[q] = idx2[bcur * 256 + (wv * 4 + q) * 16 + m16];
        float4 f0, f1, f2, f3;
        {
            const float* p = &tab0[(long)gidx[0] * 64 + quad * 8];
            f0 = *(const float4*)p;        f1 = *(const float4*)(p + 4);
            f2 = *(const float4*)(p + 32); f3 = *(const float4*)(p + 36);
        }
#pragma unroll
        for (int q = 0; q < 4; ++q) {
            const int srow = bb * 16 + wv * 4 + q;
            matmul_tile(f0, f1, f2, f3, sN[wv]);
            if (q < 3) {  // prefetch next slot's A rows; consumed next iteration
                const float* p = &tab0[(long)gidx[q + 1] * 64 + quad * 8];
                f0 = *(const float4*)p;        f1 = *(const float4*)(p + 4);
                f2 = *(const float4*)(p + 32); f3 = *(const float4*)(p + 36);
            }
            __builtin_amdgcn_wave_barrier();
            float4 c4 = *(const float4*)&sC[srow * 68 + 4 * j4];
            float4 h4 = routing_reg(sN[wv], c4, true);
            if (rr == 0)
                *(float4*)&sH[srow * 68 + 4 * j4] = h4;   // h1 row
            __builtin_amdgcn_wave_barrier();   // sN reads done before next matmul
        }
    }

    // ================= layer-0: wave 0 -> b0, wave 1 -> b1 ====================
    __syncthreads();   // the only block barrier: all h1 rows visible
    if (wv < 2) {
        const int bcur = wv ? b1 : b0;
        load_wfrag(w0n_id);
        sE0[wv][lane] = wv ? v01 : v00;
        half8 A0, A1;
        {
            const float* hp = &sH[(wv * 16 + m16) * 68];
            A0 = pack8_f16(*(const float4*)&hp[quad * 8],
                           *(const float4*)&hp[quad * 8 + 4]);
            A1 = pack8_f16(*(const float4*)&hp[32 + quad * 8],
                           *(const float4*)&hp[32 + quad * 8 + 4]);
        }
        floatx4 acc[4];
#pragma unroll
        for (int nt = 0; nt < 4; ++nt) {
            acc[nt] = (floatx4){0.f, 0.f, 0.f, 0.f};
            acc[nt] = __builtin_amdgcn_mfma_f32_16x16x32_f16(A0, wf[nt][0], acc[nt], 0, 0, 0);
            acc[nt] = __builtin_amdgcn_mfma_f32_16x16x32_f16(A1, wf[nt][1], acc[nt], 0, 0, 0);
        }
#pragma unroll
        for (int nt = 0; nt < 4; ++nt)
#pragma unroll
            for (int rg = 0; rg < 4; ++rg)
                sN[wv][(quad * 4 + rg) * 68 + nt * 16 + m16] = acc[nt][rg];
        __builtin_amdgcn_wave_barrier();
        float4 c4 = *(const float4*)&sE0[wv][4 * j4];
        float4 h4 = routing_reg(sN[wv], c4, false);
        if (rr == 0)
            *(float4*)&out[((long)branch * B + bcur) * 64 + 4 * j4] = h4;
    }
}

extern "C" void kernel_launch(void* const* d_in, const int* in_sizes, int n_in,
                              void* d_out, int out_size, void* d_ws, size_t ws_size,
                              hipStream_t stream) {
    const float* user_table = (const float*)d_in[0];
    const float* item_table = (const float*)d_in[1];
    const float* W0u = (const float*)d_in[2];
    const float* W0i = (const float*)d_in[3];
    const float* W1u = (const float*)d_in[4];
    const float* W1i = (const float*)d_in[5];
    const int* uidx0 = (const int*)d_in[6];
    const int* uidx1 = (const int*)d_in[7];
    const int* uidx2 = (const int*)d_in[8];
    const int* iidx0 = (const int*)d_in[9];
    const int* iidx1 = (const int*)d_in[10];
    const int* iidx2 = (const int*)d_in[11];
    float* out = (float*)d_out;
    half8* pk = (half8*)d_ws;   // 4 matrices * 8 frags * 64 lanes * 16B = 32 KB

    const int B = in_sizes[6];  // 2048
    hipLaunchKernelGGL(pack_weights, dim3(4), dim3(256), 0, stream,
                       W0u, W0i, W1u, W1i, pk);
    dim3 grid((B + 1) / 2, 2), block(NTH);
    hipLaunchKernelGGL(disenhan_mfma, grid, block, 0, stream,
                       user_table, item_table, (const half8*)pk,
                       uidx0, uidx1, uidx2, iidx0, iidx1, iidx2, out, B);
}